// Round 8
// baseline (44766.150 us; speedup 1.0000x reference)
//
#include <hip/hip_runtime.h>

// B=16,S=1024,C=509->IN=512,H=600; bidirectional GRU, 16384 serial steps/dir.
//
// R6 (passing, 30.0ms): 150 WG agent-scope (IC) u64 {ctr|f32} exchange, 1.78us/step.
// R7 (hang): sc0 inline-asm loads -- stale-L1 spin suspected. Lesson: never
// bet a poll loop on unverifiable cache-bit semantics.
// R8: XCD-local exchange via WORKGROUP-scope atomic RMWs (swap publish,
// fetch_add(0) poll -- atomics execute at the XCD L2, never hit L1), with
// blockIdx%8 XCD heuristic + deadline-guarded self-test + agent-scope vote.
// Unanimous pass -> fast local path; else R6-proven agent-scope path.
// New shape: 30 WGs x 1024 thr per direction (1 CU each, one XCD/dir),
// W_hh rows in VGPRs (4 rows/wave x 10 f32/lane), 1 poll slot/thread.
//
// Workspace:
//   X  @0          16,777,216
//   GX @16,777,216 58,982,400 (fp16)        end 75,759,616
//   PB @75,776,000 [2][2][600]*8 = 19,200
//   TS @75,795,200 [2][600]*8   =  9,600
//   CT @75,804,800 128B (OK@0, DONE@64B)
//   DF @75,805,056 256B
//   WB @75,805,312 1,843,200                end 77,648,512

#define HDIM   600
#define TH3    1800
#define NROWS  16384
#define KDIM   512
#define NSTEP  16384
#define KWG    30      // WGs per direction
#define EPWG   20      // h elems per WG
#define RPW    4       // rows per wave (60 rows over waves 0..14)
#define HPAD2  640

#define OFF_GX 16777216ull
#define OFF_PB 75776000ull
#define OFF_TS 75795200ull
#define OFF_CT 75804800ull
#define OFF_DF 75805056ull
#define OFF_WB 75805312ull

typedef short bf16x8 __attribute__((ext_vector_type(8)));
typedef float f32x4  __attribute__((ext_vector_type(4)));
typedef _Float16 f16;
typedef unsigned long long u64;

__device__ __forceinline__ float bf2f(unsigned short u) {
  union { unsigned u32; float f; } v; v.u32 = ((unsigned)u) << 16; return v.f;
}
__device__ __forceinline__ unsigned short f2bf(float f) {
  union { float f; unsigned u; } v; v.f = f;
  unsigned r = (v.u + 0x7FFFu + ((v.u >> 16) & 1u)) >> 16;   // RNE
  return (unsigned short)r;
}

// ---- init: pub/test/ctl + dtype detect ------------------------------------
__global__ void init_k(const unsigned short* __restrict__ ctx,
                       u64* __restrict__ pub, u64* __restrict__ tst,
                       int* __restrict__ ctl, int* __restrict__ df) {
  int i = blockIdx.x * 256 + threadIdx.x;
  if (i < 2 * 2 * HDIM) {                      // pub [d][par][600]
    int par = (i / HDIM) & 1;
    pub[i] = par ? 0x00000000FFFFFFFFull : 0ull;
  }
  if (i < 2 * HDIM) tst[i] = 0ull;
  if (i < 32) ctl[i] = 0;
  if (blockIdx.x == 0 && threadIdx.x == 0) {
    int bad = 0;
    for (int k = 0; k < 512; ++k) {
      unsigned e = (ctx[2 * k] >> 7) & 0xFFu;
      bad += (e >= 0xF0u) | (e < 0x10u);
    }
    df[0] = (bad > 0) ? 1 : 0;
  }
}

// ---- embed + concat -> X bf16 [16384][512] --------------------------------
__global__ void embed_k(const unsigned short* __restrict__ ctx,
                        const int* __restrict__ tags,
                        const unsigned short* __restrict__ temb,
                        unsigned short* __restrict__ x,
                        const int* __restrict__ df) {
  const int fp32 = df[0];
  int idx = blockIdx.x * 256 + threadIdx.x;
  int row = idx >> 9, j = idx & 511;
  unsigned short v;
  if (fp32) {
    const float* ctxF  = (const float*)ctx;
    const float* tembF = (const float*)temb;
    v = (j < 3) ? f2bf(tembF[tags[row] * 3 + j]) : f2bf(ctxF[row * 509 + (j - 3)]);
  } else {
    v = (j < 3) ? temb[tags[row] * 3 + j] : ctx[row * 509 + (j - 3)];
  }
  x[idx] = v;
}

// ---- W_ih -> bf16 ---------------------------------------------------------
__global__ void wcast_k(const unsigned short* __restrict__ wih,
                        unsigned short* __restrict__ wb,
                        const int* __restrict__ df) {
  const int fp32 = df[0];
  int i = blockIdx.x * 256 + threadIdx.x;
  wb[i] = fp32 ? f2bf(((const float*)wih)[i]) : wih[i];
}

// ---- GEMM: gx[16384][1800] = X @ W_ih^T + b_ih (fp16 out) -----------------
__global__ __launch_bounds__(256) void gemm_k(const unsigned short* __restrict__ X,
                                              const unsigned short* __restrict__ Wb,
                                              const unsigned short* __restrict__ bih,
                                              f16* __restrict__ gx,
                                              const int* __restrict__ df) {
  const int fp32 = df[0];
  const int lane = threadIdx.x & 63;
  const int wv   = threadIdx.x >> 6;
  const int mt   = blockIdx.y * 4 + wv;
  const int nt   = blockIdx.x;
  const int mrow = mt * 16 + (lane & 15);
  const int ncol = nt * 16 + (lane & 15);
  const int koff = (lane >> 4) * 8;
  const int nclamp = (ncol < TH3) ? ncol : (TH3 - 1);

  const bf16x8* ap = (const bf16x8*)(X  + (size_t)mrow   * KDIM + koff);
  const bf16x8* bp = (const bf16x8*)(Wb + (size_t)nclamp * KDIM + koff);

  f32x4 acc = {0.f, 0.f, 0.f, 0.f};
  #pragma unroll
  for (int kc = 0; kc < 16; ++kc) {
    bf16x8 av = ap[kc * 4];
    bf16x8 bv = bp[kc * 4];
    acc = __builtin_amdgcn_mfma_f32_16x16x32_bf16(av, bv, acc, 0, 0, 0);
  }
  if (ncol < TH3) {
    const float bias = fp32 ? ((const float*)bih)[ncol] : bf2f(bih[ncol]);
    const int r0 = mt * 16 + (lane >> 4) * 4;
    #pragma unroll
    for (int i = 0; i < 4; ++i)
      gx[(size_t)(r0 + i) * TH3 + ncol] = (f16)(acc[i] + bias);
  }
}

// fast-path (XCD-local) ops: atomics execute at the XCD's L2, bypass L1.
__device__ __forceinline__ u64 rd_slot(u64* p, bool fast) {
  if (fast) return __hip_atomic_fetch_add(p, 0ull, __ATOMIC_RELAXED, __HIP_MEMORY_SCOPE_WORKGROUP);
  return __hip_atomic_load(p, __ATOMIC_RELAXED, __HIP_MEMORY_SCOPE_AGENT);
}
__device__ __forceinline__ void wr_slot(u64* p, u64 v, bool fast) {
  if (fast) (void)__hip_atomic_exchange(p, v, __ATOMIC_RELAXED, __HIP_MEMORY_SCOPE_WORKGROUP);
  else __hip_atomic_store(p, v, __ATOMIC_RELAXED, __HIP_MEMORY_SCOPE_AGENT);
}

// ---- persistent bidirectional GRU recurrence ------------------------------
__global__ __launch_bounds__(1024) void gru_rec(const unsigned short* __restrict__ Whh,
                                                const unsigned short* __restrict__ bhh,
                                                const f16* __restrict__ gx,
                                                u64* __restrict__ pub,   // [2][2][600]
                                                u64* __restrict__ tst,   // [2][600]
                                                int* __restrict__ ctl,
                                                void* __restrict__ outv,
                                                const int* __restrict__ df) {
  const int tid = threadIdx.x;
  const int b   = blockIdx.x;
  const int d   = b & 7;              // XCD heuristic: blockIdx%8 = XCD
  const int k   = b >> 3;
  if (d > 1 || k >= KWG) return;      // 60 participants, rest exit
  const int fp32 = df[0];

  __shared__ __align__(16) float hlds[HPAD2];
  __shared__ float ghl[60];
  __shared__ int s_fail, s_fast;

  if (tid >= HDIM && tid < HPAD2) hlds[tid] = 0.f;   // pad stays 0 forever
  if (tid == 0) s_fail = 0;
  __syncthreads();

  // ---- self-test the local-L2 path (deadline-bounded), then agent vote ----
  {
    u64* T = tst + (size_t)d * HDIM;
    if (tid < EPWG) {
      const int e = EPWG * k + tid;
      const u64 tok = ((u64)(0x5A5A0000u | (unsigned)e) << 32) | 0x7E57ull;
      wr_slot(T + e, tok, true);
    }
    if (tid < HDIM) {
      const u64 want = ((u64)(0x5A5A0000u | (unsigned)tid) << 32) | 0x7E57ull;
      u64 t0 = __builtin_amdgcn_s_memrealtime();
      bool got = false;
      while (!got) {
        if (rd_slot(T + tid, true) == want) { got = true; break; }
        if (__builtin_amdgcn_s_memrealtime() - t0 > 50000ull) break;  // ~0.5ms
      }
      if (!got) s_fail = 1;
    }
    __syncthreads();
    if (tid == 0) {
      __hip_atomic_fetch_add(ctl, (s_fail ? 0 : 1), __ATOMIC_RELAXED, __HIP_MEMORY_SCOPE_AGENT);
      __hip_atomic_fetch_add(ctl + 16, 1, __ATOMIC_RELAXED, __HIP_MEMORY_SCOPE_AGENT);
      while (__hip_atomic_load(ctl + 16, __ATOMIC_RELAXED, __HIP_MEMORY_SCOPE_AGENT) < 2 * KWG) {}
      s_fast = (__hip_atomic_load(ctl, __ATOMIC_RELAXED, __HIP_MEMORY_SCOPE_AGENT) == 2 * KWG) ? 1 : 0;
    }
    __syncthreads();
  }
  const bool fast = (s_fast != 0);

  // ---- load W_hh rows into VGPRs: wave wv<15 holds rows j=wv*4+s ----------
  const int lane = tid & 63;
  const int wv   = tid >> 6;
  const bool has_rows = (wv < 15);
  float wreg[RPW][10];
  if (has_rows) {
    #pragma unroll
    for (int s = 0; s < RPW; ++s) {
      const int j = wv * RPW + s;                 // 0..59
      const int g = j / EPWG, i = j % EPWG;
      const size_t grow = (size_t)(g * HDIM + EPWG * k + i) * HDIM;
      #pragma unroll
      for (int q = 0; q < 10; ++q) {
        const int kk = 10 * lane + q;
        if (kk < HDIM)
          wreg[s][q] = fp32 ? ((const float*)Whh)[grow + kk] : bf2f(Whh[grow + kk]);
        else wreg[s][q] = 0.f;
      }
    }
  }
  float bhr = 0.f, bhz = 0.f, bhn = 0.f;
  if (tid < EPWG) {
    const int e = EPWG * k + tid;
    if (fp32) {
      const float* bF = (const float*)bhh;
      bhr = bF[e]; bhz = bF[HDIM + e]; bhn = bF[2 * HDIM + e];
    } else {
      bhr = bf2f(bhh[e]); bhz = bf2f(bhh[HDIM + e]); bhn = bf2f(bhh[2 * HDIM + e]);
    }
  }

  float hold = 0.f;
  for (int t = 0; t < NSTEP; ++t) {
    // prefetch gx (independent of h; hides under poll)
    float gxr = 0.f, gxz = 0.f, gxn = 0.f;
    if (tid < EPWG) {
      const int rw = (d == 0) ? t : (((t >> 10) << 10) + (1023 - (t & 1023)));
      const f16* p = gx + (size_t)rw * TH3 + EPWG * k + tid;
      gxr = (float)p[0]; gxz = (float)p[HDIM]; gxn = (float)p[2 * HDIM];
    }
    // poll: 1 slot per thread (tid<600)
    if (tid < HDIM) {
      u64* slot = pub + (size_t)(d * 2 + (t & 1)) * HDIM + tid;
      const unsigned ut = (unsigned)t;
      u64 v = rd_slot(slot, fast);
      while ((unsigned)v != ut) v = rd_slot(slot, fast);
      union { unsigned u; float f; } cv; cv.u = (unsigned)(v >> 32);
      hlds[tid] = cv.f;
    }
    __syncthreads();
    // dots: 4 rows/wave, 10 h/lane, 64-lane shuffle reduce
    if (has_rows) {
      float h10[10];
      const float2* hp = (const float2*)(hlds + 10 * lane);
      #pragma unroll
      for (int q = 0; q < 5; ++q) { float2 h2 = hp[q]; h10[2*q] = h2.x; h10[2*q+1] = h2.y; }
      #pragma unroll
      for (int s = 0; s < RPW; ++s) {
        float acc = 0.f;
        #pragma unroll
        for (int q = 0; q < 10; ++q) acc += wreg[s][q] * h10[q];
        acc += __shfl_xor(acc, 1);
        acc += __shfl_xor(acc, 2);
        acc += __shfl_xor(acc, 4);
        acc += __shfl_xor(acc, 8);
        acc += __shfl_xor(acc, 16);
        acc += __shfl_xor(acc, 32);
        if (lane == 0) ghl[wv * RPW + s] = acc;
      }
    }
    __syncthreads();
    // gates + publish h_{t+1}
    if (tid < EPWG) {
      const float rr  = 1.f / (1.f + __expf(-(gxr + ghl[tid] + bhr)));
      const float zz  = 1.f / (1.f + __expf(-(gxz + ghl[EPWG + tid] + bhz)));
      const float pre = gxn + rr * (ghl[2 * EPWG + tid] + bhn);
      const float nn  = 1.f - 2.f / (1.f + __expf(2.f * pre));   // tanh
      const float hn  = nn + zz * (hold - nn);
      hold = hn;
      union { float f; unsigned u; } hv; hv.f = hn;
      const u64 pk = ((u64)hv.u << 32) | (unsigned)(t + 1);
      wr_slot(pub + (size_t)(d * 2 + ((t + 1) & 1)) * HDIM + EPWG * k + tid, pk, fast);
      if (t == NSTEP - 1) {
        const int o = d * HDIM + EPWG * k + tid;
        if (fp32) ((float*)outv)[o] = hn;
        else      ((unsigned short*)outv)[o] = f2bf(hn);
      }
    }
    // no trailing barrier: hlds/ghl step-t reads all precede barrier2 (R5 note)
  }
}

extern "C" void kernel_launch(void* const* d_in, const int* in_sizes, int n_in,
                              void* d_out, int out_size, void* d_ws, size_t ws_size,
                              hipStream_t stream) {
  const unsigned short* ctx  = (const unsigned short*)d_in[0];
  const int*            tags = (const int*)d_in[1];
  const unsigned short* temb = (const unsigned short*)d_in[2];
  const unsigned short* wih  = (const unsigned short*)d_in[3];
  const unsigned short* whh  = (const unsigned short*)d_in[4];
  const unsigned short* bih  = (const unsigned short*)d_in[5];
  const unsigned short* bhh  = (const unsigned short*)d_in[6];

  char* ws = (char*)d_ws;
  unsigned short* X  = (unsigned short*)ws;
  f16*            GX = (f16*)(ws + OFF_GX);
  u64*            PB = (u64*)  (ws + OFF_PB);
  u64*            TS = (u64*)  (ws + OFF_TS);
  int*            CT = (int*)  (ws + OFF_CT);
  int*            DF = (int*)  (ws + OFF_DF);
  unsigned short* WB = (unsigned short*)(ws + OFF_WB);

  init_k <<<32, 256, 0, stream>>>(ctx, PB, TS, CT, DF);
  embed_k<<<(NROWS * KDIM) / 256, 256, 0, stream>>>(ctx, tags, temb, X, DF);
  wcast_k<<<(TH3 * KDIM) / 256, 256, 0, stream>>>(wih, WB, DF);
  gemm_k <<<dim3(113, 256), 256, 0, stream>>>(X, WB, bih, GX, DF);
  gru_rec<<<240, 1024, 0, stream>>>(whh, bhh, GX, PB, TS, CT, d_out, DF);
}